// Round 10
// baseline (327.223 us; speedup 1.0000x reference)
//
#include <hip/hip_runtime.h>
#include <math.h>

// Problem constants
#define T_  204
#define I_  5
#define H_  24
#define L_  10
#define O_  612
#define Bsz 8192

typedef _Float16 half8 __attribute__((ext_vector_type(8)));
typedef _Float16 half2t __attribute__((ext_vector_type(2)));
typedef float    float4t __attribute__((ext_vector_type(4)));

union U16B { float4t f4; half8 h8; float f[4]; _Float16 h[8]; half2t h2[4]; };

__device__ __forceinline__ float fast_rcp(float x){ return __builtin_amdgcn_rcpf(x); }
__device__ __forceinline__ float fast_ex2(float x){ return __builtin_amdgcn_exp2f(x); }
__device__ __forceinline__ half2t pk2(float a, float b){
    return __builtin_bit_cast(half2t, __builtin_amdgcn_cvt_pkrtz(a, b));
}

#define MFMA16(a,b,c) __builtin_amdgcn_mfma_f32_16x16x32_f16((a),(b),(c),0,0,0)

#define L2E  1.44269504f
#define L2E2 2.88539008f

__device__ __forceinline__ float sigm2(float x){ return fast_rcp(1.f + fast_ex2(x * -L2E)); }
__device__ __forceinline__ float tanh2(float x){ return 2.f * fast_rcp(1.f + fast_ex2(x * -L2E2)) - 1.f; }

// R9 post-mortem: per-step wall (1740 cyc) is a serial latency chain (MFMA
// readback + dependent exp2/rcp + DS round-trip), fully exposed at 1 wave/SIMD;
// issue is only ~650 cyc. Fix: ILP-2 -- each wave runs TWO independent
// 16-element groups; group B's issue fills group A's stall slots. Single wave
// per block (R9's 2-wave split was neutral: different SIMDs can't share stalls).
__global__ __launch_bounds__(64)
__attribute__((amdgpu_waves_per_eu(1, 2)))
void lstm_mfma(const float* __restrict__ x,
               const float* __restrict__ W_ih,
               const float* __restrict__ W_hh,
               const float* __restrict__ b_ih,
               const float* __restrict__ b_hh,
               const float* __restrict__ fc0_w,
               const float* __restrict__ fc0_b,
               const float* __restrict__ out_w,
               const float* __restrict__ out_b,
               float* __restrict__ out)
{
    __shared__ __align__(16) _Float16 hL[2][16*40];   // per-group h staging (80B rows)
    __shared__ __align__(16) _Float16 actL[2][16*24];

    const int lane = threadIdx.x;
    const int m = lane & 15;        // element col / A row-within-tile
    const int q = lane >> 4;        // quad
    const int elemA = blockIdx.x * 32 + m;
    const int elemB = elemA + 16;

    const float4t zf4 = {0.f, 0.f, 0.f, 0.f};

    // ---- gate A-fragments, unit-ownership permutation (validated R8) ----
    // packed row mm of tile T = gate (mm&3) of unit 6*(mm>>2)+T; lane (m,q)'s
    // D reg r of tile T = gate r of unit 6q+T -> cell update fully in-lane.
    half8 Ag[6];
    const int g0 = m & 3, ub = 6 * (m >> 2);
    #pragma unroll
    for (int T6 = 0; T6 < 6; ++T6) {
        const int srow = g0 * H_ + ub + T6;
        float wv[8];
        if (q < 3) {
            const float4t* pw = (const float4t*)(W_hh + srow*H_ + 8*q);
            float4t wa = pw[0], wb = pw[1];
            #pragma unroll
            for (int i = 0; i < 4; ++i) { wv[i] = wa[i]; wv[4+i] = wb[i]; }
        } else {
            #pragma unroll
            for (int i = 0; i < 8; ++i) wv[i] = 0.f;
            #pragma unroll
            for (int i = 0; i < I_; ++i) wv[i] = W_ih[srow*I_ + i];
            wv[5] = b_ih[srow] + b_hh[srow];
        }
        U16B tw;
        #pragma unroll
        for (int i = 0; i < 8; ++i) tw.h[i] = (_Float16)wv[i];
        Ag[T6] = tw.h8;
    }

    const int hwIdx = m*40 + 6*q;     // scatter: units 6q..6q+5 (consecutive)
    const int hrIdx = m*40 + 8*q;     // gather: b128 (q<3)

    const float* xpA = x + (size_t)elemA * (T_*I_);
    const float* xpB = x + (size_t)elemB * (T_*I_);

    // ---- fc0 inline loads: lane (m<10, q<3) owns A[m][8q..8q+7] ----
    const bool fval = (m < L_) && (q < 3);
    const float* fbase = fc0_w + (size_t)(m < L_ ? m : 0) * (T_*H_) + 8*q;
    float4t fA0 = zf4, fA1 = zf4;
    if (fval) {
        fA0 = *(const float4t*)(fbase + 0);
        fA1 = *(const float4t*)(fbase + 4);
    }

    // ---- initial B-frags: [h=0 | x_0 | 1 | 0,0] ----
    U16B BA, BB;
    if (q == 3) {
        BA.h2[0] = pk2(xpA[0], xpA[1]);
        BA.h2[1] = pk2(xpA[2], xpA[3]);
        BA.h2[2] = pk2(xpA[4], 1.0f);
        BA.h2[3] = pk2(0.f, 0.f);
        BB.h2[0] = pk2(xpB[0], xpB[1]);
        BB.h2[1] = pk2(xpB[2], xpB[3]);
        BB.h2[2] = pk2(xpB[4], 1.0f);
        BB.h2[3] = pk2(0.f, 0.f);
    } else {
        BA.f4 = zf4; BB.f4 = zf4;
    }

    float cA[6] = {0,0,0,0,0,0}, cB[6] = {0,0,0,0,0,0};
    float4t accA = zf4, accB = zf4;

    // ================= time loop =================
    for (int t = 0; t < T_; ++t) {
        // prefetch next-step operands (consumed at iteration bottom)
        const int tn = (t + 1 < T_) ? t + 1 : t;
        float xa[I_] = {0,0,0,0,0}, xb[I_] = {0,0,0,0,0};
        if (q == 3) {
            const float* xqa = xpA + tn*I_;
            const float* xqb = xpB + tn*I_;
            #pragma unroll
            for (int i = 0; i < I_; ++i) { xa[i] = xqa[i]; xb[i] = xqb[i]; }
        }
        float4t fN0 = zf4, fN1 = zf4;
        if (fval) {
            fN0 = *(const float4t*)(fbase + tn*H_ + 0);
            fN1 = *(const float4t*)(fbase + tn*H_ + 4);
        }

        // gate MFMAs, both groups (independent chains)
        float4t DA0 = MFMA16(Ag[0], BA.h8, zf4);
        float4t DB0 = MFMA16(Ag[0], BB.h8, zf4);
        float4t DA1 = MFMA16(Ag[1], BA.h8, zf4);
        float4t DB1 = MFMA16(Ag[1], BB.h8, zf4);
        float4t DA2 = MFMA16(Ag[2], BA.h8, zf4);
        float4t DB2 = MFMA16(Ag[2], BB.h8, zf4);
        float4t DA3 = MFMA16(Ag[3], BA.h8, zf4);
        float4t DB3 = MFMA16(Ag[3], BB.h8, zf4);
        float4t DA4 = MFMA16(Ag[4], BA.h8, zf4);
        float4t DB4 = MFMA16(Ag[4], BB.h8, zf4);
        float4t DA5 = MFMA16(Ag[5], BA.h8, zf4);
        float4t DB5 = MFMA16(Ag[5], BB.h8, zf4);

        // in-lane cell updates; interleave A/B so chains overlap
        {
            float4t DA[6] = {DA0, DA1, DA2, DA3, DA4, DA5};
            float4t DB[6] = {DB0, DB1, DB2, DB3, DB4, DB5};
            #pragma unroll
            for (int T6 = 0; T6 < 6; ++T6) {
                const float siA = sigm2(DA[T6][0]);
                const float siB = sigm2(DB[T6][0]);
                const float sfA = sigm2(DA[T6][1]);
                const float sfB = sigm2(DB[T6][1]);
                const float tgA = tanh2(DA[T6][2]);
                const float tgB = tanh2(DB[T6][2]);
                const float soA = sigm2(DA[T6][3]);
                const float soB = sigm2(DB[T6][3]);
                cA[T6] = fmaf(sfA, cA[T6], siA * tgA);
                cB[T6] = fmaf(sfB, cB[T6], siB * tgB);
                const float hA = soA * tanh2(cA[T6]);
                const float hB = soB * tanh2(cB[T6]);
                hL[0][hwIdx + T6] = (_Float16)hA;
                hL[1][hwIdx + T6] = (_Float16)hB;
            }
        }
        __builtin_amdgcn_wave_barrier();   // order scatter before gather (in-order DS)

        // rebuild B-frags
        if (q < 3) {
            BA.f4 = *(const float4t*)(&hL[0][hrIdx]);
            BB.f4 = *(const float4t*)(&hL[1][hrIdx]);
        } else {
            BA.h2[0] = pk2(xa[0], xa[1]);
            BA.h2[1] = pk2(xa[2], xa[3]);
            BA.h2[2] = pk2(xa[4], 1.0f);
            BA.h2[3] = pk2(0.f, 0.f);
            BB.h2[0] = pk2(xb[0], xb[1]);
            BB.h2[1] = pk2(xb[2], xb[3]);
            BB.h2[2] = pk2(xb[4], 1.0f);
            BB.h2[3] = pk2(0.f, 0.f);
        }

        // fc0 accumulation with h_t (shared A-frag, both groups)
        U16B fF;
        fF.h2[0] = pk2(fA0[0], fA0[1]);
        fF.h2[1] = pk2(fA0[2], fA0[3]);
        fF.h2[2] = pk2(fA1[0], fA1[1]);
        fF.h2[3] = pk2(fA1[2], fA1[3]);
        accA = MFMA16(fF.h8, BA.h8, accA);
        accB = MFMA16(fF.h8, BB.h8, accB);

        fA0 = fN0; fA1 = fN1;
    }

    // ================= epilogue =================
    #pragma unroll
    for (int r = 0; r < 4; ++r) {
        const int l = 4*q + r;
        if (l < L_) {
            const float fb = fc0_b[l];
            actL[0][m*24 + l] = (_Float16)fmaxf(accA[r] + fb, 0.f);
            actL[1][m*24 + l] = (_Float16)fmaxf(accB[r] + fb, 0.f);
        } else if (l < 16) {   // zero-pad k=10..15 so zero A rows never hit poison
            actL[0][m*24 + l] = (_Float16)0.f;
            actL[1][m*24 + l] = (_Float16)0.f;
        }
    }
    __builtin_amdgcn_wave_barrier();

    U16B BaA, BaB;
    if (q < 2) {
        BaA.f4 = *(const float4t*)(&actL[0][m*24 + 8*q]);
        BaB.f4 = *(const float4t*)(&actL[1][m*24 + 8*q]);
    } else {
        BaA.f4 = zf4; BaB.f4 = zf4;    // k>=16 unused (A-frag zero there)
    }

    // out = act @ out_w^T + out_b : 39 tiles; weight frag shared across groups
    for (int Tt = 0; Tt < 39; ++Tt) {
        const int row = 16*Tt + m;
        float w0=0.f,w1=0.f,w2=0.f,w3=0.f,w4=0.f,w5=0.f,w6=0.f,w7=0.f;
        if (row < O_ && q < 2) {
            const float2* p2 = (const float2*)(out_w + row*L_);
            if (q == 0) {
                float2 a = p2[0], b = p2[1], cc = p2[2], dd = p2[3];
                w0=a.x; w1=a.y; w2=b.x; w3=b.y; w4=cc.x; w5=cc.y; w6=dd.x; w7=dd.y;
            } else {
                float2 a = p2[4];
                w0=a.x; w1=a.y;
            }
        }
        U16B Aw;
        Aw.h2[0] = pk2(w0,w1); Aw.h2[1] = pk2(w2,w3);
        Aw.h2[2] = pk2(w4,w5); Aw.h2[3] = pk2(w6,w7);

        float4t ddA = MFMA16(Aw.h8, BaA.h8, zf4);
        float4t ddB = MFMA16(Aw.h8, BaB.h8, zf4);

        const int ob = 16*Tt + 4*q;
        if (ob < O_) {
            const float4t bias = *(const float4t*)(out_b + ob);
            #pragma unroll
            for (int r = 0; r < 4; ++r) { ddA[r] += bias[r]; ddB[r] += bias[r]; }
            *(float4t*)(out + (size_t)elemA*O_ + ob) = ddA;
            *(float4t*)(out + (size_t)elemB*O_ + ob) = ddB;
        }
    }
}

extern "C" void kernel_launch(void* const* d_in, const int* in_sizes, int n_in,
                              void* d_out, int out_size, void* d_ws, size_t ws_size,
                              hipStream_t stream)
{
    const float* x     = (const float*)d_in[0];
    const float* W_ih  = (const float*)d_in[1];
    const float* W_hh  = (const float*)d_in[2];
    const float* b_ih  = (const float*)d_in[3];
    const float* b_hh  = (const float*)d_in[4];
    const float* fc0_w = (const float*)d_in[5];
    const float* fc0_b = (const float*)d_in[6];
    const float* out_w = (const float*)d_in[7];
    const float* out_b = (const float*)d_in[8];
    float* out = (float*)d_out;
    (void)d_ws; (void)ws_size;

    lstm_mfma<<<dim3(Bsz/32), dim3(64), 0, stream>>>(
        x, W_ih, W_hh, b_ih, b_hh, fc0_w, fc0_b, out_w, out_b, out);
}

// Round 11
// 221.113 us; speedup vs baseline: 1.4799x; 1.4799x over previous
//
#include <hip/hip_runtime.h>
#include <math.h>

// Problem constants
#define T_  204
#define I_  5
#define H_  24
#define L_  10
#define O_  612
#define Bsz 8192

typedef _Float16 half8 __attribute__((ext_vector_type(8)));
typedef _Float16 half2t __attribute__((ext_vector_type(2)));
typedef float    float4t __attribute__((ext_vector_type(4)));

union U16B { float4t f4; half8 h8; float f[4]; _Float16 h[8]; half2t h2[4]; };

__device__ __forceinline__ float fast_rcp(float x){ return __builtin_amdgcn_rcpf(x); }
__device__ __forceinline__ float fast_ex2(float x){ return __builtin_amdgcn_exp2f(x); }
__device__ __forceinline__ half2t pk2(float a, float b){
    return __builtin_bit_cast(half2t, __builtin_amdgcn_cvt_pkrtz(a, b));
}

#define MFMA16(a,b,c) __builtin_amdgcn_mfma_f32_16x16x32_f16((a),(b),(c),0,0,0)

#define L2E  1.44269504f
#define L2E2 2.88539008f

__device__ __forceinline__ float sigm2(float x){ return fast_rcp(1.f + fast_ex2(x * -L2E)); }
__device__ __forceinline__ float tanh2(float x){ return 2.f * fast_rcp(1.f + fast_ex2(x * -L2E2)) - 1.f; }

// Unit owned by lane-quad q, tile T (q<3: 8q+T; q==3: overflow units 6,7,14,15,22,23)
__device__ __forceinline__ int unit_of(int q, int T) {
    return (q < 3) ? (8*q + T) : (8*(T >> 1) + 6 + (T & 1));
}

// Prepack fc0_w into per-timestep fp16 A-fragments (A[m=l][k=j], zeros elsewhere).
__global__ __launch_bounds__(64)
void pack_fc0(const float* __restrict__ fc0_w, float4t* __restrict__ dst)
{
    const int t = blockIdx.x, lane = threadIdx.x;
    const int m = lane & 15, q = lane >> 4;
    U16B v;
    #pragma unroll
    for (int i = 0; i < 8; ++i) {
        const int k = 8*q + i;
        float f = (m < L_ && k < H_) ? fc0_w[m*(T_*H_) + t*H_ + k] : 0.0f;
        v.h[i] = (_Float16)f;
    }
    dst[t*64 + lane] = v.f4;
}

// R10 post-mortem: per-step wall = issue + ~1000 cyc of chain stalls. R11 cuts
// the chain links: (1) unit-ownership remap so lane (m,q<3) computes exactly
// the units its own B-slot needs -> h redistribution is 3 ds_bpermute shuffles
// (no barrier, no LDS round-trip); (2) depth-2 x prefetch (~2 iters > 900-cyc
// HBM latency); (3) prepacked fc0 frags (1 b128 load, no cvt). R8's 512x64 shape.
__global__ __launch_bounds__(64)
void lstm_mfma(const float* __restrict__ x,
               const float* __restrict__ W_ih,
               const float* __restrict__ W_hh,
               const float* __restrict__ b_ih,
               const float* __restrict__ b_hh,
               const float* __restrict__ fc0_b,
               const float* __restrict__ out_w,
               const float* __restrict__ out_b,
               const float4t* __restrict__ fc0A,   // prepacked in d_ws
               float* __restrict__ out)
{
    __shared__ __align__(16) _Float16 actL[16*24];  // epilogue staging only

    const int lane = threadIdx.x;
    const int m = lane & 15;        // element col / A row-within-tile
    const int q = lane >> 4;        // quad
    const int elem = blockIdx.x * 16 + m;

    const float4t zf4 = {0.f, 0.f, 0.f, 0.f};

    // ---- gate A-fragments ----
    // Packed row mm of tile T = gate (mm&3) of unit unit_of(mm>>2, T), so the
    // lane's D reg r of tile T = gate r of unit unit_of(q, T): cell update
    // in-lane AND (for q<3) the owned units 8q+T are exactly this lane's
    // B-slots k=8q..8q+5. k-slice: k<24 W_hh, 24..28 W_ih, 29 bias, 30,31 zero.
    half8 Ag[6];
    #pragma unroll
    for (int T6 = 0; T6 < 6; ++T6) {
        const int u = unit_of(m >> 2, T6);
        const int srow = (m & 3) * H_ + u;       // torch gate-major row
        float wv[8];
        if (q < 3) {
            const float4t* pw = (const float4t*)(W_hh + srow*H_ + 8*q);
            float4t wa = pw[0], wb = pw[1];
            #pragma unroll
            for (int i = 0; i < 4; ++i) { wv[i] = wa[i]; wv[4+i] = wb[i]; }
        } else {
            #pragma unroll
            for (int i = 0; i < 8; ++i) wv[i] = 0.f;
            #pragma unroll
            for (int i = 0; i < I_; ++i) wv[i] = W_ih[srow*I_ + i];
            wv[5] = b_ih[srow] + b_hh[srow];
        }
        U16B tw;
        #pragma unroll
        for (int i = 0; i < 8; ++i) tw.h[i] = (_Float16)wv[i];
        Ag[T6] = tw.h8;
    }

    const float* xp = x + (size_t)elem * (T_*I_);

    // ---- initial B-frag [h=0 | x_0 | 1 | 0,0]; x prefetch ring (depth 2) ----
    U16B B;
    if (q == 3) {
        B.h2[0] = pk2(xp[0], xp[1]);
        B.h2[1] = pk2(xp[2], xp[3]);
        B.h2[2] = pk2(xp[4], 1.0f);
        B.h2[3] = pk2(0.f, 0.f);
    } else {
        B.f4 = zf4;
    }
    float xC[I_] = {0,0,0,0,0};              // x(t+1), consumed at iter bottom
    if (q == 3) {
        #pragma unroll
        for (int i = 0; i < I_; ++i) xC[i] = xp[I_ + i];
    }

    float c_[6] = {0,0,0,0,0,0};
    float4t accF = zf4;
    float4t fa = fc0A[lane];                 // fc0 frag for t=0

    // ================= time loop (no barriers, no LDS) =================
    for (int t = 0; t < T_; ++t) {
        // prefetches: x(t+2) [~2 iters ahead, covers HBM ~900cyc], fc0 frag t+1
        const int tn = (t + 1 < T_) ? t + 1 : t;
        const float4t fan = fc0A[tn*64 + lane];
        float xN[I_] = {0,0,0,0,0};
        if (q == 3) {
            const int tp2 = (t + 2 < T_) ? t + 2 : T_ - 1;
            const float* xq = xp + tp2*I_;
            #pragma unroll
            for (int i = 0; i < I_; ++i) xN[i] = xq[i];
        }

        // 6 gate MFMAs
        float4t D0 = MFMA16(Ag[0], B.h8, zf4);
        float4t D1 = MFMA16(Ag[1], B.h8, zf4);
        float4t D2 = MFMA16(Ag[2], B.h8, zf4);
        float4t D3 = MFMA16(Ag[3], B.h8, zf4);
        float4t D4 = MFMA16(Ag[4], B.h8, zf4);
        float4t D5 = MFMA16(Ag[5], B.h8, zf4);

        // in-lane cell update for this lane's 6 owned units
        float hh[6];
        {
            float4t D[6] = {D0, D1, D2, D3, D4, D5};
            #pragma unroll
            for (int T6 = 0; T6 < 6; ++T6) {
                const float si = sigm2(D[T6][0]);
                const float sf = sigm2(D[T6][1]);
                const float tg = tanh2(D[T6][2]);
                const float so = sigm2(D[T6][3]);
                c_[T6] = fmaf(sf, c_[T6], si * tg);
                hh[T6] = so * tanh2(c_[T6]);
            }
        }

        // pack own h pairs; q3's pairs are the overflow units consumers need:
        // P0 = (u6,u7) -> q0's k-slots 6,7; P1 = (u14,u15) -> q1; P2 = (u22,u23) -> q2
        const float P0 = __builtin_bit_cast(float, pk2(hh[0], hh[1]));
        const float P1 = __builtin_bit_cast(float, pk2(hh[2], hh[3]));
        const float P2 = __builtin_bit_cast(float, pk2(hh[4], hh[5]));

        // fetch overflow pair from lane (m, q=3) = lane 48+m (3 bpermutes, no barrier)
        const int src = 48 + m;
        const float r0 = __shfl(P0, src, 64);
        const float r1 = __shfl(P1, src, 64);
        const float r2 = __shfl(P2, src, 64);
        const float rcv = (q == 0) ? r0 : ((q == 1) ? r1 : r2);

        // rebuild B-frag
        if (q < 3) {
            B.h2[0] = __builtin_bit_cast(half2t, P0);   // units 8q+0,1
            B.h2[1] = __builtin_bit_cast(half2t, P1);   // units 8q+2,3
            B.h2[2] = __builtin_bit_cast(half2t, P2);   // units 8q+4,5
            B.h2[3] = __builtin_bit_cast(half2t, rcv);  // units 8q+6,7 (from q3)
        } else {
            B.h2[0] = pk2(xC[0], xC[1]);
            B.h2[1] = pk2(xC[2], xC[3]);
            B.h2[2] = pk2(xC[4], 1.0f);
            B.h2[3] = pk2(0.f, 0.f);
        }

        // fc0 accumulation with h_t (fc0A rows k>=24 are zero)
        U16B fF; fF.f4 = fa;
        accF = MFMA16(fF.h8, B.h8, accF);

        fa = fan;
        #pragma unroll
        for (int i = 0; i < I_; ++i) xC[i] = xN[i];
    }

    // ================= epilogue (validated R7/R8) =================
    float av[4];
    #pragma unroll
    for (int r = 0; r < 4; ++r) {
        const int l = 4*q + r;
        const float fb = (l < L_) ? fc0_b[l] : 0.f;
        const float v = accF[r] + fb;
        av[r] = (l < L_) ? fmaxf(v, 0.f) : 0.f;
    }
    *(half2t*)(&actL[m*24 + 4*q])     = pk2(av[0], av[1]);
    *(half2t*)(&actL[m*24 + 4*q + 2]) = pk2(av[2], av[3]);
    __builtin_amdgcn_wave_barrier();

    U16B Ba;
    if (q < 2) Ba.f4 = *(const float4t*)(&actL[m*24 + q*8]);
    else       Ba.f4 = zf4;            // k>=16 unused (out_w A-frag zero there)

    for (int Tt = 0; Tt < 39; ++Tt) {
        const int row = 16*Tt + m;
        float w0=0.f,w1=0.f,w2=0.f,w3=0.f,w4=0.f,w5=0.f,w6=0.f,w7=0.f;
        if (row < O_ && q < 2) {
            const float2* p2 = (const float2*)(out_w + row*L_);
            if (q == 0) {
                float2 a = p2[0], b = p2[1], cc = p2[2], dd = p2[3];
                w0=a.x; w1=a.y; w2=b.x; w3=b.y; w4=cc.x; w5=cc.y; w6=dd.x; w7=dd.y;
            } else {
                float2 a = p2[4];
                w0=a.x; w1=a.y;
            }
        }
        U16B Aw;
        Aw.h2[0] = pk2(w0,w1); Aw.h2[1] = pk2(w2,w3);
        Aw.h2[2] = pk2(w4,w5); Aw.h2[3] = pk2(w6,w7);

        float4t dd = MFMA16(Aw.h8, Ba.h8, zf4);

        const int ob = 16*Tt + 4*q;
        if (ob < O_) {
            const float4t bias = *(const float4t*)(out_b + ob);
            #pragma unroll
            for (int r = 0; r < 4; ++r) dd[r] += bias[r];
            *(float4t*)(out + (size_t)elem*O_ + ob) = dd;
        }
    }
}

extern "C" void kernel_launch(void* const* d_in, const int* in_sizes, int n_in,
                              void* d_out, int out_size, void* d_ws, size_t ws_size,
                              hipStream_t stream)
{
    const float* x     = (const float*)d_in[0];
    const float* W_ih  = (const float*)d_in[1];
    const float* W_hh  = (const float*)d_in[2];
    const float* b_ih  = (const float*)d_in[3];
    const float* b_hh  = (const float*)d_in[4];
    const float* fc0_w = (const float*)d_in[5];
    const float* fc0_b = (const float*)d_in[6];
    const float* out_w = (const float*)d_in[7];
    const float* out_b = (const float*)d_in[8];
    float* out = (float*)d_out;
    (void)ws_size;

    pack_fc0<<<dim3(T_), dim3(64), 0, stream>>>(fc0_w, (float4t*)d_ws);
    lstm_mfma<<<dim3(Bsz/16), dim3(64), 0, stream>>>(
        x, W_ih, W_hh, b_ih, b_hh, fc0_b, out_w, out_b,
        (const float4t*)d_ws, out);
}